// Round 8
// baseline (1061.647 us; speedup 1.0000x reference)
//
#include <hip/hip_runtime.h>
#include <cstdint>
#include <cstddef>

typedef unsigned long long u64;

// ---------------- prep 1: W2 transpose (f32, + zero row 256) + folded output weights ----------------
__global__ void prep_weights(const float* __restrict__ W2, const float* __restrict__ Wc2,
                             const float* __restrict__ bc2, const float* __restrict__ WA,
                             float* __restrict__ Wt2f, double* __restrict__ wEff,
                             double* __restrict__ bEff)
{
  int id = blockIdx.x * 256 + (int)threadIdx.x;
  if (id < 65536){ int i = id >> 8, j = id & 255; Wt2f[(i<<8)+j] = W2[j*256+i]; }  // Wt2f[i][j] = W2[j][i]
  else if (id < 65792){ Wt2f[id] = 0.0f; }                                          // zero row (idx 256)
  if (id < 32){ double s = 0.0; for (int c=0;c<64;c++) s += (double)WA[c]*(double)Wc2[c*32+id]; wEff[id] = s; }
  if (id == 32){ double s = 0.0; for (int c=0;c<64;c++) s += (double)WA[c]*(double)bc2[c]; *bEff = s; }
}

// ---------------- prep 2: rate-encode probabilities (f64) ----------------
__global__ void prep_probs(const float* __restrict__ x, double* __restrict__ probs, int B)
{
  int b = blockIdx.x, k = (int)threadIdx.x;
  if (b >= B || k >= 24) return;
  double* pb = probs + (size_t)b*24;
  if (k >= 18){ pb[k] = -1.0; return; }
  int fk, g0, gn;
  if (k < 12){ fk = k;          g0 = 0;  gn = 12; }
  else if (k < 15){ fk = 6+(k-12);  g0 = 6;  gn = 6; }
  else           { fk = 12+(k-15); g0 = 12; gn = 6; }
  const float* xb = x + (size_t)b*18;
  double mn = (double)xb[g0], mx = mn;
  for (int f = 1; f < gn; f++){ double v = (double)xb[g0+f]; mn = fmin(mn, v); mx = fmax(mx, v); }
  double rng = mx - mn; if (rng == 0.0) rng = 1.0;
  double norm = ((double)xb[fk] - mn) / rng;
  double p = (100.0 * norm) * 0.001;
  p = fmin(fmax(p, 0.0), 1.0);
  pb[k] = p;
}

// ---------------- prep 3: pack spike bits, TRANSPOSED to (b, t), t-padded with 2 zeros ----------------
__global__ void prep_enc(const float* __restrict__ u1, const float* __restrict__ u2,
                         const float* __restrict__ u3, const double* __restrict__ probs,
                         unsigned* __restrict__ encT, int B, int T)
{
  int b = blockIdx.x * blockDim.x + (int)threadIdx.x;
  int t = blockIdx.y;
  if (b >= B) return;
  if (t >= T){ encT[(size_t)b*(T+2) + t] = 0u; return; }
  const double* pb = probs + (size_t)b*24;
  size_t r = (size_t)t * B + b;
  const float* a1 = u1 + r*12;
  const float* a2 = u2 + r*6;
  const float* a3 = u3 + r*6;
  unsigned e = 0;
  #pragma unroll
  for (int k = 0; k < 12; k++) if ((double)a1[k] < pb[k])    e |= (1u << k);
  #pragma unroll
  for (int h = 0; h < 3; h++)  if ((double)a2[h] < pb[12+h]) e |= (1u << (12+h));
  #pragma unroll
  for (int h = 0; h < 3; h++)  if ((double)a3[h] < pb[15+h]) e |= (1u << (15+h));
  encT[(size_t)b*(T+2) + t] = e;
}

// ---------------- main: one wave per batch row (R3 structure) ----------------
// R7: cross-mask CASCADE extraction for L2/L3 gather windows — each 4-wide window
// processes 4 REAL spike rows (padding only in the final window), eliminating the
// zero-row pad loads+f64 adds of the per-mask scheme. Extraction is branchless
// SALU (ctz + cselect cascade), zero VGPR growth -> 8 waves/SIMD preserved.
__global__ __launch_bounds__(256) void snn_main(
    const unsigned* __restrict__ encT,
    const float* __restrict__ b1, const float* __restrict__ b2, const float* __restrict__ b3,
    const float* __restrict__ W1, const float* __restrict__ W3,
    const float* __restrict__ Wc1, const float* __restrict__ bc1,
    const float* __restrict__ Wt2f,
    const double* __restrict__ wEff, const double* __restrict__ bEff,
    float* __restrict__ out, int B, int T)
{
  __shared__ __align__(16) float s_w1[12*256];   // s_w1[k][j] = W1[j][k]
  __shared__ __align__(16) float s_w3[257*4];    // s_w3[i][c] = W3[c][i] (c<3), col3 + row256 = 0

  const int tid  = (int)threadIdx.x;
  const int lane = tid & 63;
  const int wid  = tid >> 6;
  const int b = blockIdx.x * 4 + wid;
  const int l4 = lane << 2;
  const int lcl = (lane < 3) ? lane : 3;

  for (int i = tid; i < 3072; i += 256){ int k = i >> 8, j = i & 255; s_w1[i] = W1[j*12+k]; }
  for (int i = tid; i < 1028; i += 256){
    int r = i >> 2, c = i & 3;
    s_w3[i] = (r < 256 && c < 3) ? W3[c*256 + r] : 0.0f;
  }
  __syncthreads();
  if (b >= B) return;

  const float4 b1f = *(const float4*)(b1 + l4);
  const float4 b2f = *(const float4*)(b2 + l4);
  const double b1d0=b1f.x, b1d1=b1f.y, b1d2=b1f.z, b1d3=b1f.w;
  const double b2d0=b2f.x, b2d1=b2f.y, b2d2=b2f.z, b2d3=b2f.w;
  const double b3d = (lane < 3) ? (double)b3[lane] : 0.0;
  double wc1b=0.0, wEd=0.0, pre0=0.0, pre1=0.0, pre2=0.0, pre3=0.0;
  if (lane < 32){
    double wa = (double)Wc1[lane*3+0];
    wc1b      = (double)Wc1[lane*3+1];
    double wc = (double)Wc1[lane*3+2];
    double bd = (double)bc1[lane];
    wEd  = wEff[lane];
    pre0 = bd;            // td=0, td2=0
    pre1 = bd + wa;       // td=1, td2=0
    pre2 = bd + wc;       // td=0, td2=1
    pre3 = bd + wa + wc;  // td=1, td2=1
  }

  double m10=0,m11=0,m12=0,m13=0;
  double m20=0,m21=0,m22=0,m23=0;
  double m3v=0;
  double m40=0,m41=0,m42=0;
  bool sp20=false,sp21=false,sp22=false,sp23=false;
  bool sp3v=false;
  bool sp40=false,sp41=false,sp42=false;

  const unsigned* encTb = encT + (size_t)b * (T + 2);

  unsigned e_cur = __builtin_amdgcn_readfirstlane(encTb[0]);
  unsigned e_nx  = __builtin_amdgcn_readfirstlane(encTb[1]);
  double ca0=b1d0, ca1=b1d1, ca2=b1d2, ca3=b1d3;
  {
    unsigned w = e_cur & 0xFFFu;
    while (w){
      int k = __builtin_ctz(w); w &= w-1;
      const float4 r = *(const float4*)&s_w1[(k<<8) + l4];
      ca0 += (double)r.x; ca1 += (double)r.y; ca2 += (double)r.z; ca3 += (double)r.w;
    }
  }

  // Branchless cross-mask cascade: pulls next set bit from w0 -> w1 -> w2 -> w3m.
  // ROW = 256 (zero row) only when all masks empty. ctz guarded with MSB-set
  // (doesn't change ctz for nonzero masks; result unused when mask empty).
  const u64 MSB = 0x8000000000000000ull;
#define EXTRACT(W0,W1,W2,W3,ROW) { \
    u64 t0_=(W0)&((W0)-1), t1_=(W1)&((W1)-1), t2_=(W2)&((W2)-1), t3_=(W3)&((W3)-1); \
    int p0_=(int)__builtin_ctzll((W0)|MSB), p1_=(int)__builtin_ctzll((W1)|MSB); \
    int p2_=(int)__builtin_ctzll((W2)|MSB), p3_=(int)__builtin_ctzll((W3)|MSB); \
    ROW = (W0) ? (p0_<<2) : (W1) ? ((p1_<<2)|1) : (W2) ? ((p2_<<2)|2) : (W3) ? ((p3_<<2)|3) : 256; \
    W3 = ((W0)|(W1)|(W2)) ? (W3) : t3_; \
    W2 = ((W0)|(W1)) ? (W2) : t2_; \
    W1 = (W0) ? (W1) : t1_; \
    W0 = t0_; }

  for (int t = 0; t < T; t++){
    // ---- layer 1 membrane update (current pre-accumulated in ca*) ----
    m10 = fma(0.9, m10, ca0);
    m11 = fma(0.9, m11, ca1);
    m12 = fma(0.9, m12, ca2);
    m13 = fma(0.9, m13, ca3);
    const bool sp10 = m10 > 1.0; u64 w0 = __ballot(sp10);
    const bool sp11 = m11 > 1.0; u64 w1 = __ballot(sp11);
    const bool sp12 = m12 > 1.0; u64 w2 = __ballot(sp12);
    const bool sp13 = m13 > 1.0; u64 w3m = __ballot(sp13);

    // ---- layer 2, first window: 4 real rows via cascade (zero row only if <4 spikes) ----
    int i0, i1, i2, i3;
    EXTRACT(w0, w1, w2, w3m, i0)
    EXTRACT(w0, w1, w2, w3m, i1)
    EXTRACT(w0, w1, w2, w3m, i2)
    EXTRACT(w0, w1, w2, w3m, i3)
    const float4 g0 = *(const float4*)(Wt2f + ((size_t)i0<<8) + l4);
    const float4 g1 = *(const float4*)(Wt2f + ((size_t)i1<<8) + l4);
    const float4 g2 = *(const float4*)(Wt2f + ((size_t)i2<<8) + l4);
    const float4 g3 = *(const float4*)(Wt2f + ((size_t)i3<<8) + l4);

    // prefetch enc for t+2 (sequential 4B, L1-hot; padded rows give 0 past T-1)
    const unsigned e_n2 = encTb[t+2];

    // ---- overlap first-window latency: next-step layer-1 gather from LDS ----
    ca0 = (sp10 ? -1.0 : 0.0) + b1d0;
    ca1 = (sp11 ? -1.0 : 0.0) + b1d1;
    ca2 = (sp12 ? -1.0 : 0.0) + b1d2;
    ca3 = (sp13 ? -1.0 : 0.0) + b1d3;
    {
      unsigned w = e_nx & 0xFFFu;
      while (w){
        int k = __builtin_ctz(w); w &= w-1;
        const float4 r = *(const float4*)&s_w1[(k<<8) + l4];
        ca0 += (double)r.x; ca1 += (double)r.y; ca2 += (double)r.z; ca3 += (double)r.w;
      }
    }

    // ---- consume first window ----
    double c0 = (sp20 ? -1.0 : 0.0) + b2d0;
    double c1 = (sp21 ? -1.0 : 0.0) + b2d1;
    double c2 = (sp22 ? -1.0 : 0.0) + b2d2;
    double c3 = (sp23 ? -1.0 : 0.0) + b2d3;
    c0 += (double)g0.x; c1 += (double)g0.y; c2 += (double)g0.z; c3 += (double)g0.w;
    c0 += (double)g1.x; c1 += (double)g1.y; c2 += (double)g1.z; c3 += (double)g1.w;
    c0 += (double)g2.x; c1 += (double)g2.y; c2 += (double)g2.z; c3 += (double)g2.w;
    c0 += (double)g3.x; c1 += (double)g3.y; c2 += (double)g3.z; c3 += (double)g3.w;

    // ---- remaining windows: all-real rows via cascade ----
    while (w0 | w1 | w2 | w3m){
      int j0, j1, j2, j3;
      EXTRACT(w0, w1, w2, w3m, j0)
      EXTRACT(w0, w1, w2, w3m, j1)
      EXTRACT(w0, w1, w2, w3m, j2)
      EXTRACT(w0, w1, w2, w3m, j3)
      const float4 h0 = *(const float4*)(Wt2f + ((size_t)j0<<8) + l4);
      const float4 h1 = *(const float4*)(Wt2f + ((size_t)j1<<8) + l4);
      const float4 h2 = *(const float4*)(Wt2f + ((size_t)j2<<8) + l4);
      const float4 h3 = *(const float4*)(Wt2f + ((size_t)j3<<8) + l4);
      c0 += (double)h0.x; c1 += (double)h0.y; c2 += (double)h0.z; c3 += (double)h0.w;
      c0 += (double)h1.x; c1 += (double)h1.y; c2 += (double)h1.z; c3 += (double)h1.w;
      c0 += (double)h2.x; c1 += (double)h2.y; c2 += (double)h2.z; c3 += (double)h2.w;
      c0 += (double)h3.x; c1 += (double)h3.y; c2 += (double)h3.z; c3 += (double)h3.w;
    }

    m20 = fma(0.9, m20, c0);
    m21 = fma(0.9, m21, c1);
    m22 = fma(0.9, m22, c2);
    m23 = fma(0.9, m23, c3);
    sp20 = m20 > 1.0; u64 v0 = __ballot(sp20);
    sp21 = m21 > 1.0; u64 v1 = __ballot(sp21);
    sp22 = m22 > 1.0; u64 v2 = __ballot(sp22);
    sp23 = m23 > 1.0; u64 v3 = __ballot(sp23);

    // ---- layer 3 from LDS: cascade windows (all-real rows) ----
    double cl3 = (sp3v ? -1.0 : 0.0) + b3d;
    while (v0 | v1 | v2 | v3){
      int j0, j1, j2, j3;
      EXTRACT(v0, v1, v2, v3, j0)
      EXTRACT(v0, v1, v2, v3, j1)
      EXTRACT(v0, v1, v2, v3, j2)
      EXTRACT(v0, v1, v2, v3, j3)
      cl3 += (double)s_w3[(j0<<2) + lcl];
      cl3 += (double)s_w3[(j1<<2) + lcl];
      cl3 += (double)s_w3[(j2<<2) + lcl];
      cl3 += (double)s_w3[(j3<<2) + lcl];
    }
    m3v = fma(0.9, m3v, cl3);
    sp3v = m3v > 1.0;
    const unsigned s3 = (unsigned)(__ballot((lane < 3) && sp3v) & 7ull);

    // ---- layer 4 (conv1 LIF): lane<32 = out-channel o, h = 0..2 ----
    const unsigned td  = (e_cur >> 12) & 7u;
    const unsigned td2 = (e_cur >> 15) & 7u;
    {
      double cur, t1, t2;
      t1 = (td2 & 1u) ? pre2 : pre0;  t2 = (td2 & 1u) ? pre3 : pre1;
      cur = (td & 1u) ? t2 : t1;
      if (s3 & 1u) cur += wc1b;
      cur += sp40 ? -1.0 : 0.0;
      m40 = fma(0.9, m40, cur); sp40 = m40 > 1.0;
      t1 = (td2 & 2u) ? pre2 : pre0;  t2 = (td2 & 2u) ? pre3 : pre1;
      cur = (td & 2u) ? t2 : t1;
      if (s3 & 2u) cur += wc1b;
      cur += sp41 ? -1.0 : 0.0;
      m41 = fma(0.9, m41, cur); sp41 = m41 > 1.0;
      t1 = (td2 & 4u) ? pre2 : pre0;  t2 = (td2 & 4u) ? pre3 : pre1;
      cur = (td & 4u) ? t2 : t1;
      if (s3 & 4u) cur += wc1b;
      cur += sp42 ? -1.0 : 0.0;
      m42 = fma(0.9, m42, cur); sp42 = m42 > 1.0;
    }

    // ---- rotate enc pipeline ----
    e_cur = e_nx;
    e_nx  = __builtin_amdgcn_readfirstlane(e_n2);
  }

  // ---- output: out[b,m] = bEff + sum_o spk4_final[o,m] * wEff[o] ----
  double o0 = sp40 ? wEd : 0.0;
  double o1 = sp41 ? wEd : 0.0;
  double o2 = sp42 ? wEd : 0.0;
  for (int off = 32; off > 0; off >>= 1){
    o0 += __shfl_xor(o0, off, 64);
    o1 += __shfl_xor(o1, off, 64);
    o2 += __shfl_xor(o2, off, 64);
  }
  if (lane == 0){
    const double be = *bEff;
    out[b*3+0] = (float)(o0 + be);
    out[b*3+1] = (float)(o1 + be);
    out[b*3+2] = (float)(o2 + be);
  }
}

// ---------------- host ----------------
extern "C" void kernel_launch(void* const* d_in, const int* in_sizes, int n_in,
                              void* d_out, int out_size, void* d_ws, size_t ws_size,
                              hipStream_t stream)
{
  const float* x   = (const float*)d_in[0];
  const float* u1  = (const float*)d_in[1];
  const float* u2  = (const float*)d_in[2];
  const float* u3  = (const float*)d_in[3];
  const float* W1  = (const float*)d_in[4];
  const float* b1  = (const float*)d_in[5];
  const float* W2  = (const float*)d_in[6];
  const float* b2  = (const float*)d_in[7];
  const float* W3  = (const float*)d_in[8];
  const float* b3  = (const float*)d_in[9];
  const float* Wc1 = (const float*)d_in[10];
  const float* bc1 = (const float*)d_in[11];
  const float* Wc2 = (const float*)d_in[12];
  const float* bc2 = (const float*)d_in[13];
  const float* WA  = (const float*)d_in[14];
  float* out = (float*)d_out;

  const int B = in_sizes[0] / 18;
  const int T = in_sizes[1] / (B * 12);

  char* ws = (char*)d_ws;
  float*  Wt2f  = (float*)(ws + 0);                        // 257*256*4 = 263168
  double* wEff  = (double*)(ws + 263168);                  // 256
  double* bEff  = (double*)(ws + 263424);                  // 8
  double* probs = (double*)(ws + 263432);                  // B*24*8
  unsigned* encT= (unsigned*)(ws + 263432 + (size_t)B*24*8); // B*(T+2)*4

  hipLaunchKernelGGL(prep_weights, dim3(257), dim3(256), 0, stream,
                     W2, Wc2, bc2, WA, Wt2f, wEff, bEff);
  hipLaunchKernelGGL(prep_probs, dim3(B), dim3(64), 0, stream, x, probs, B);
  hipLaunchKernelGGL(prep_enc, dim3((B+255)/256, T+2), dim3(256), 0, stream,
                     u1, u2, u3, probs, encT, B, T);
  hipLaunchKernelGGL(snn_main, dim3((B+3)/4), dim3(256), 0, stream,
                     encT, b1, b2, b3, W1, W3, Wc1, bc1, Wt2f, wEff, bEff, out, B, T);
}

// Round 9
// 684.762 us; speedup vs baseline: 1.5504x; 1.5504x over previous
//
#include <hip/hip_runtime.h>
#include <cstdint>
#include <cstddef>

typedef unsigned long long u64;

// ---------------- prep 1: W2 transpose (f32, + zero row 256) + folded output weights ----------------
__global__ void prep_weights(const float* __restrict__ W2, const float* __restrict__ Wc2,
                             const float* __restrict__ bc2, const float* __restrict__ WA,
                             float* __restrict__ Wt2f, double* __restrict__ wEff,
                             double* __restrict__ bEff)
{
  int id = blockIdx.x * 256 + (int)threadIdx.x;
  if (id < 65536){ int i = id >> 8, j = id & 255; Wt2f[(i<<8)+j] = W2[j*256+i]; }  // Wt2f[i][j] = W2[j][i]
  else if (id < 65792){ Wt2f[id] = 0.0f; }                                          // zero row (idx 256)
  if (id < 32){ double s = 0.0; for (int c=0;c<64;c++) s += (double)WA[c]*(double)Wc2[c*32+id]; wEff[id] = s; }
  if (id == 32){ double s = 0.0; for (int c=0;c<64;c++) s += (double)WA[c]*(double)bc2[c]; *bEff = s; }
}

// ---------------- prep 2: rate-encode probabilities (f64) ----------------
__global__ void prep_probs(const float* __restrict__ x, double* __restrict__ probs, int B)
{
  int b = blockIdx.x, k = (int)threadIdx.x;
  if (b >= B || k >= 24) return;
  double* pb = probs + (size_t)b*24;
  if (k >= 18){ pb[k] = -1.0; return; }
  int fk, g0, gn;
  if (k < 12){ fk = k;          g0 = 0;  gn = 12; }
  else if (k < 15){ fk = 6+(k-12);  g0 = 6;  gn = 6; }
  else           { fk = 12+(k-15); g0 = 12; gn = 6; }
  const float* xb = x + (size_t)b*18;
  double mn = (double)xb[g0], mx = mn;
  for (int f = 1; f < gn; f++){ double v = (double)xb[g0+f]; mn = fmin(mn, v); mx = fmax(mx, v); }
  double rng = mx - mn; if (rng == 0.0) rng = 1.0;
  double norm = ((double)xb[fk] - mn) / rng;
  double p = (100.0 * norm) * 0.001;
  p = fmin(fmax(p, 0.0), 1.0);
  pb[k] = p;
}

// ---------------- prep 3: pack spike bits, TRANSPOSED to (b, t), t-padded with 2 zeros ----------------
__global__ void prep_enc(const float* __restrict__ u1, const float* __restrict__ u2,
                         const float* __restrict__ u3, const double* __restrict__ probs,
                         unsigned* __restrict__ encT, int B, int T)
{
  int b = blockIdx.x * blockDim.x + (int)threadIdx.x;
  int t = blockIdx.y;
  if (b >= B) return;
  if (t >= T){ encT[(size_t)b*(T+2) + t] = 0u; return; }
  const double* pb = probs + (size_t)b*24;
  size_t r = (size_t)t * B + b;
  const float* a1 = u1 + r*12;
  const float* a2 = u2 + r*6;
  const float* a3 = u3 + r*6;
  unsigned e = 0;
  #pragma unroll
  for (int k = 0; k < 12; k++) if ((double)a1[k] < pb[k])    e |= (1u << k);
  #pragma unroll
  for (int h = 0; h < 3; h++)  if ((double)a2[h] < pb[12+h]) e |= (1u << (12+h));
  #pragma unroll
  for (int h = 0; h < 3; h++)  if ((double)a3[h] < pb[15+h]) e |= (1u << (15+h));
  encT[(size_t)b*(T+2) + t] = e;
}

// ---------------- main: one wave per batch row (R3 structure) ----------------
// R8 = R3 + wave-uniform skip of padded-slot ARITHMETIC. Loads stay unconditional
// (zero-row is L1-hot; preserves R3's parallel load issue — R7's serial-extract
// mistake is not repeated). Only the 8 f64 ops per padded slot are branched around
// via scalar-uniform conditions (i/j == 256).
__global__ __launch_bounds__(256) void snn_main(
    const unsigned* __restrict__ encT,
    const float* __restrict__ b1, const float* __restrict__ b2, const float* __restrict__ b3,
    const float* __restrict__ W1, const float* __restrict__ W3,
    const float* __restrict__ Wc1, const float* __restrict__ bc1,
    const float* __restrict__ Wt2f,
    const double* __restrict__ wEff, const double* __restrict__ bEff,
    float* __restrict__ out, int B, int T)
{
  __shared__ __align__(16) float s_w1[12*256];   // s_w1[k][j] = W1[j][k]
  __shared__ __align__(16) float s_w3[257*4];    // s_w3[i][c] = W3[c][i] (c<3), col3 + row256 = 0

  const int tid  = (int)threadIdx.x;
  const int lane = tid & 63;
  const int wid  = tid >> 6;
  const int b = blockIdx.x * 4 + wid;
  const int l4 = lane << 2;
  const int lcl = (lane < 3) ? lane : 3;

  for (int i = tid; i < 3072; i += 256){ int k = i >> 8, j = i & 255; s_w1[i] = W1[j*12+k]; }
  for (int i = tid; i < 1028; i += 256){
    int r = i >> 2, c = i & 3;
    s_w3[i] = (r < 256 && c < 3) ? W3[c*256 + r] : 0.0f;
  }
  __syncthreads();
  if (b >= B) return;

  const float4 b1f = *(const float4*)(b1 + l4);
  const float4 b2f = *(const float4*)(b2 + l4);
  const double b1d0=b1f.x, b1d1=b1f.y, b1d2=b1f.z, b1d3=b1f.w;
  const double b2d0=b2f.x, b2d1=b2f.y, b2d2=b2f.z, b2d3=b2f.w;
  const double b3d = (lane < 3) ? (double)b3[lane] : 0.0;
  double wc1b=0.0, wEd=0.0, pre0=0.0, pre1=0.0, pre2=0.0, pre3=0.0;
  if (lane < 32){
    double wa = (double)Wc1[lane*3+0];
    wc1b      = (double)Wc1[lane*3+1];
    double wc = (double)Wc1[lane*3+2];
    double bd = (double)bc1[lane];
    wEd  = wEff[lane];
    pre0 = bd;            // td=0, td2=0
    pre1 = bd + wa;       // td=1, td2=0
    pre2 = bd + wc;       // td=0, td2=1
    pre3 = bd + wa + wc;  // td=1, td2=1
  }

  double m10=0,m11=0,m12=0,m13=0;
  double m20=0,m21=0,m22=0,m23=0;
  double m3v=0;
  double m40=0,m41=0,m42=0;
  bool sp20=false,sp21=false,sp22=false,sp23=false;
  bool sp3v=false;
  bool sp40=false,sp41=false,sp42=false;

  const unsigned* encTb = encT + (size_t)b * (T + 2);

  unsigned e_cur = __builtin_amdgcn_readfirstlane(encTb[0]);
  unsigned e_nx  = __builtin_amdgcn_readfirstlane(encTb[1]);
  double ca0=b1d0, ca1=b1d1, ca2=b1d2, ca3=b1d3;
  {
    unsigned w = e_cur & 0xFFFu;
    while (w){
      int k = __builtin_ctz(w); w &= w-1;
      const float4 r = *(const float4*)&s_w1[(k<<8) + l4];
      ca0 += (double)r.x; ca1 += (double)r.y; ca2 += (double)r.z; ca3 += (double)r.w;
    }
  }

  for (int t = 0; t < T; t++){
    // ---- layer 1 membrane update (current pre-accumulated in ca*) ----
    m10 = fma(0.9, m10, ca0);
    m11 = fma(0.9, m11, ca1);
    m12 = fma(0.9, m12, ca2);
    m13 = fma(0.9, m13, ca3);
    const bool sp10 = m10 > 1.0; u64 w0 = __ballot(sp10);
    const bool sp11 = m11 > 1.0; u64 w1 = __ballot(sp11);
    const bool sp12 = m12 > 1.0; u64 w2 = __ballot(sp12);
    const bool sp13 = m13 > 1.0; u64 w3m = __ballot(sp13);

    // ---- layer 2, first window: one row per CW-mask (zero-row 256 when empty) ----
    int i0 = w0  ? (((int)__builtin_ctzll(w0) <<2)|0) : 256;  w0  &= w0 -1;
    int i1 = w1  ? (((int)__builtin_ctzll(w1) <<2)|1) : 256;  w1  &= w1 -1;
    int i2 = w2  ? (((int)__builtin_ctzll(w2) <<2)|2) : 256;  w2  &= w2 -1;
    int i3 = w3m ? (((int)__builtin_ctzll(w3m)<<2)|3) : 256;  w3m &= w3m-1;
    const float4 g0 = *(const float4*)(Wt2f + ((size_t)i0<<8) + l4);
    const float4 g1 = *(const float4*)(Wt2f + ((size_t)i1<<8) + l4);
    const float4 g2 = *(const float4*)(Wt2f + ((size_t)i2<<8) + l4);
    const float4 g3 = *(const float4*)(Wt2f + ((size_t)i3<<8) + l4);

    // prefetch enc for t+2 (sequential 4B, L1-hot; padded rows give 0 past T-1)
    const unsigned e_n2 = encTb[t+2];

    // ---- overlap first-window latency: next-step layer-1 gather from LDS ----
    ca0 = (sp10 ? -1.0 : 0.0) + b1d0;
    ca1 = (sp11 ? -1.0 : 0.0) + b1d1;
    ca2 = (sp12 ? -1.0 : 0.0) + b1d2;
    ca3 = (sp13 ? -1.0 : 0.0) + b1d3;
    {
      unsigned w = e_nx & 0xFFFu;
      while (w){
        int k = __builtin_ctz(w); w &= w-1;
        const float4 r = *(const float4*)&s_w1[(k<<8) + l4];
        ca0 += (double)r.x; ca1 += (double)r.y; ca2 += (double)r.z; ca3 += (double)r.w;
      }
    }

    // ---- consume first window: skip padded slots (wave-uniform branches) ----
    double c0 = (sp20 ? -1.0 : 0.0) + b2d0;
    double c1 = (sp21 ? -1.0 : 0.0) + b2d1;
    double c2 = (sp22 ? -1.0 : 0.0) + b2d2;
    double c3 = (sp23 ? -1.0 : 0.0) + b2d3;
    if (i0 != 256){ c0 += (double)g0.x; c1 += (double)g0.y; c2 += (double)g0.z; c3 += (double)g0.w; }
    if (i1 != 256){ c0 += (double)g1.x; c1 += (double)g1.y; c2 += (double)g1.z; c3 += (double)g1.w; }
    if (i2 != 256){ c0 += (double)g2.x; c1 += (double)g2.y; c2 += (double)g2.z; c3 += (double)g2.w; }
    if (i3 != 256){ c0 += (double)g3.x; c1 += (double)g3.y; c2 += (double)g3.z; c3 += (double)g3.w; }

    // ---- remaining windows: loads unconditional, consumes guarded ----
    while (w0 | w1 | w2 | w3m){
      int j0 = w0  ? (((int)__builtin_ctzll(w0) <<2)|0) : 256;  w0  &= w0 -1;
      int j1 = w1  ? (((int)__builtin_ctzll(w1) <<2)|1) : 256;  w1  &= w1 -1;
      int j2 = w2  ? (((int)__builtin_ctzll(w2) <<2)|2) : 256;  w2  &= w2 -1;
      int j3 = w3m ? (((int)__builtin_ctzll(w3m)<<2)|3) : 256;  w3m &= w3m-1;
      const float4 h0 = *(const float4*)(Wt2f + ((size_t)j0<<8) + l4);
      const float4 h1 = *(const float4*)(Wt2f + ((size_t)j1<<8) + l4);
      const float4 h2 = *(const float4*)(Wt2f + ((size_t)j2<<8) + l4);
      const float4 h3 = *(const float4*)(Wt2f + ((size_t)j3<<8) + l4);
      if (j0 != 256){ c0 += (double)h0.x; c1 += (double)h0.y; c2 += (double)h0.z; c3 += (double)h0.w; }
      if (j1 != 256){ c0 += (double)h1.x; c1 += (double)h1.y; c2 += (double)h1.z; c3 += (double)h1.w; }
      if (j2 != 256){ c0 += (double)h2.x; c1 += (double)h2.y; c2 += (double)h2.z; c3 += (double)h2.w; }
      if (j3 != 256){ c0 += (double)h3.x; c1 += (double)h3.y; c2 += (double)h3.z; c3 += (double)h3.w; }
    }

    m20 = fma(0.9, m20, c0);
    m21 = fma(0.9, m21, c1);
    m22 = fma(0.9, m22, c2);
    m23 = fma(0.9, m23, c3);
    sp20 = m20 > 1.0; u64 v0 = __ballot(sp20);
    sp21 = m21 > 1.0; u64 v1 = __ballot(sp21);
    sp22 = m22 > 1.0; u64 v2 = __ballot(sp22);
    sp23 = m23 > 1.0; u64 v3 = __ballot(sp23);

    // ---- layer 3 from LDS: consumes guarded per slot ----
    double cl3 = (sp3v ? -1.0 : 0.0) + b3d;
    while (v0 | v1 | v2 | v3){
      int j0 = v0 ? (((int)__builtin_ctzll(v0)<<2)|0) : 256;  v0 &= v0-1;
      int j1 = v1 ? (((int)__builtin_ctzll(v1)<<2)|1) : 256;  v1 &= v1-1;
      int j2 = v2 ? (((int)__builtin_ctzll(v2)<<2)|2) : 256;  v2 &= v2-1;
      int j3 = v3 ? (((int)__builtin_ctzll(v3)<<2)|3) : 256;  v3 &= v3-1;
      if (j0 != 256) cl3 += (double)s_w3[(j0<<2) + lcl];
      if (j1 != 256) cl3 += (double)s_w3[(j1<<2) + lcl];
      if (j2 != 256) cl3 += (double)s_w3[(j2<<2) + lcl];
      if (j3 != 256) cl3 += (double)s_w3[(j3<<2) + lcl];
    }
    m3v = fma(0.9, m3v, cl3);
    sp3v = m3v > 1.0;
    const unsigned s3 = (unsigned)(__ballot((lane < 3) && sp3v) & 7ull);

    // ---- layer 4 (conv1 LIF): lane<32 = out-channel o, h = 0..2 ----
    const unsigned td  = (e_cur >> 12) & 7u;
    const unsigned td2 = (e_cur >> 15) & 7u;
    {
      double cur, t1, t2;
      t1 = (td2 & 1u) ? pre2 : pre0;  t2 = (td2 & 1u) ? pre3 : pre1;
      cur = (td & 1u) ? t2 : t1;
      if (s3 & 1u) cur += wc1b;
      cur += sp40 ? -1.0 : 0.0;
      m40 = fma(0.9, m40, cur); sp40 = m40 > 1.0;
      t1 = (td2 & 2u) ? pre2 : pre0;  t2 = (td2 & 2u) ? pre3 : pre1;
      cur = (td & 2u) ? t2 : t1;
      if (s3 & 2u) cur += wc1b;
      cur += sp41 ? -1.0 : 0.0;
      m41 = fma(0.9, m41, cur); sp41 = m41 > 1.0;
      t1 = (td2 & 4u) ? pre2 : pre0;  t2 = (td2 & 4u) ? pre3 : pre1;
      cur = (td & 4u) ? t2 : t1;
      if (s3 & 4u) cur += wc1b;
      cur += sp42 ? -1.0 : 0.0;
      m42 = fma(0.9, m42, cur); sp42 = m42 > 1.0;
    }

    // ---- rotate enc pipeline ----
    e_cur = e_nx;
    e_nx  = __builtin_amdgcn_readfirstlane(e_n2);
  }

  // ---- output: out[b,m] = bEff + sum_o spk4_final[o,m] * wEff[o] ----
  double o0 = sp40 ? wEd : 0.0;
  double o1 = sp41 ? wEd : 0.0;
  double o2 = sp42 ? wEd : 0.0;
  for (int off = 32; off > 0; off >>= 1){
    o0 += __shfl_xor(o0, off, 64);
    o1 += __shfl_xor(o1, off, 64);
    o2 += __shfl_xor(o2, off, 64);
  }
  if (lane == 0){
    const double be = *bEff;
    out[b*3+0] = (float)(o0 + be);
    out[b*3+1] = (float)(o1 + be);
    out[b*3+2] = (float)(o2 + be);
  }
}

// ---------------- host ----------------
extern "C" void kernel_launch(void* const* d_in, const int* in_sizes, int n_in,
                              void* d_out, int out_size, void* d_ws, size_t ws_size,
                              hipStream_t stream)
{
  const float* x   = (const float*)d_in[0];
  const float* u1  = (const float*)d_in[1];
  const float* u2  = (const float*)d_in[2];
  const float* u3  = (const float*)d_in[3];
  const float* W1  = (const float*)d_in[4];
  const float* b1  = (const float*)d_in[5];
  const float* W2  = (const float*)d_in[6];
  const float* b2  = (const float*)d_in[7];
  const float* W3  = (const float*)d_in[8];
  const float* b3  = (const float*)d_in[9];
  const float* Wc1 = (const float*)d_in[10];
  const float* bc1 = (const float*)d_in[11];
  const float* Wc2 = (const float*)d_in[12];
  const float* bc2 = (const float*)d_in[13];
  const float* WA  = (const float*)d_in[14];
  float* out = (float*)d_out;

  const int B = in_sizes[0] / 18;
  const int T = in_sizes[1] / (B * 12);

  char* ws = (char*)d_ws;
  float*  Wt2f  = (float*)(ws + 0);                        // 257*256*4 = 263168
  double* wEff  = (double*)(ws + 263168);                  // 256
  double* bEff  = (double*)(ws + 263424);                  // 8
  double* probs = (double*)(ws + 263432);                  // B*24*8
  unsigned* encT= (unsigned*)(ws + 263432 + (size_t)B*24*8); // B*(T+2)*4

  hipLaunchKernelGGL(prep_weights, dim3(257), dim3(256), 0, stream,
                     W2, Wc2, bc2, WA, Wt2f, wEff, bEff);
  hipLaunchKernelGGL(prep_probs, dim3(B), dim3(64), 0, stream, x, probs, B);
  hipLaunchKernelGGL(prep_enc, dim3((B+255)/256, T+2), dim3(256), 0, stream,
                     u1, u2, u3, probs, encT, B, T);
  hipLaunchKernelGGL(snn_main, dim3((B+3)/4), dim3(256), 0, stream,
                     encT, b1, b2, b3, W1, W3, Wc1, bc1, Wt2f, wEff, bEff, out, B, T);
}